// Round 7
// baseline (135.559 us; speedup 1.0000x reference)
//
#include <hip/hip_runtime.h>
#include <hip/hip_bf16.h>

// Problem constants
#define S_LEN 2048
#define NHEAD 16
#define HDIM  64
#define DMODEL 1024

typedef unsigned short u16;
typedef __attribute__((ext_vector_type(8))) short short8;   // 8 x bf16 (4 VGPRs)
typedef __attribute__((ext_vector_type(4))) float floatx4;
typedef __attribute__((ext_vector_type(4))) u16 u16x4;

__device__ __forceinline__ u16 f2bf(float f) {
  unsigned u = __builtin_bit_cast(unsigned, f);
  u += 0x7fffu + ((u >> 16) & 1u);
  return (u16)(u >> 16);
}
__device__ __forceinline__ float bf2f(u16 b) {
  unsigned u = ((unsigned)b) << 16;
  return __builtin_bit_cast(float, u);
}
__device__ __forceinline__ void gload_lds16(const void* g, void* l) {
  __builtin_amdgcn_global_load_lds((const __attribute__((address_space(1))) unsigned int*)g,
                                   (__attribute__((address_space(3))) unsigned int*)l,
                                   16, 0, 0);
}
// XOR swizzle: spread row bits into the 16B-slot bits (involution, 16B granularity).
// Verified R2/R3: SQ_LDS_BANK_CONFLICT == 0 on both 64B-row (GEMM) and 128B-row (attn) tiles.
// For reads the mask is LANE-CONSTANT (proved: row bits 7-9 depend only on lane),
// so read addresses are precomputed bases + immediate offsets (no per-read VALU).
__device__ __forceinline__ int swz(int b) { return b ^ (((b >> 7) & 7) << 4); }

#define MFMA16(a, b, c) __builtin_amdgcn_mfma_f32_16x16x32_bf16(a, b, c, 0, 0, 0)

// ---------------- conversion kernels ----------------

__global__ __launch_bounds__(256) void k_cast(const float* __restrict__ in,
                                              u16* __restrict__ hi, int n) {
  int i = (blockIdx.x * blockDim.x + threadIdx.x) * 4;
  if (i >= n) return;
  float4 v = *(const float4*)(in + i);
  u16x4 hv = {f2bf(v.x), f2bf(v.y), f2bf(v.z), f2bf(v.w)};
  *(u16x4*)(hi + i) = hv;
}

// in: [R][C] f32  ->  oh: [C][R] bf16 (transposed)
__global__ void k_transpose(const float* __restrict__ in, u16* __restrict__ oh, int R, int C) {
  __shared__ float t[32][33];
  int c0 = blockIdx.x * 32, r0 = blockIdx.y * 32;
  int tx = threadIdx.x, ty = threadIdx.y;
#pragma unroll
  for (int rr = ty; rr < 32; rr += 8) t[rr][tx] = in[(size_t)(r0 + rr) * C + c0 + tx];
  __syncthreads();
#pragma unroll
  for (int rr = ty; rr < 32; rr += 8) {
    float v = t[tx][rr];
    oh[(size_t)(c0 + rr) * R + r0 + tx] = f2bf(v);
  }
}

// ---------------- bf16 GEMM mainloop (counted-vmcnt pipeline) ----------------
// C[128x128] = A[128x1024] * B^T, B stored [N][K=1024].
// 3 LDS buffers, prefetch depth 2, ONE raw s_barrier per K-step, never vmcnt(0) in loop.
__device__ __forceinline__ void gemm_main(const u16* __restrict__ A, const u16* __restrict__ B,
                                          int m0, int n0, floatx4 (&acc)[4][4]) {
  __shared__ __align__(16) u16 sA[3][128 * 32];
  __shared__ __align__(16) u16 sB[3][128 * 32];
  const int tid = threadIdx.x, lane = tid & 63;
  const int wid = tid >> 6, wr = wid >> 1, wc = wid & 1;
  const int cl = lane & 15, hi = lane >> 4;
  // hoisted swizzled read bases: b = w*4096 + i*1024 + cl*64 + hi*16, (b>>7)&7 == (cl>>1)&7
  const int rmask = ((cl >> 1) & 7) << 4;
  const int aoff = (wr * 4096 + cl * 64 + hi * 16) ^ rmask;
  const int boff = (wc * 4096 + cl * 64 + hi * 16) ^ rmask;
#pragma unroll
  for (int i = 0; i < 4; ++i)
#pragma unroll
    for (int j = 0; j < 4; ++j) acc[i][j] = (floatx4){0.f, 0.f, 0.f, 0.f};

  auto stage = [&](int buf, int kt) {   // 4 loads/thread
    int k0 = kt * 32;
#pragma unroll
    for (int it = 0; it < 2; ++it) {
      // linear LDS dest; source address pre-swizzled so swizzled reads see consistent data
      int p = (it * 256 + tid) * 16;
      int q = swz(p);
      int row = q >> 6, colb = q & 63;
      int base = (it * 256 + (tid & ~63)) * 16;   // wave-uniform LDS base (HW adds lane*16)
      gload_lds16((const char*)A + (size_t)(m0 + row) * 2048 + k0 * 2 + colb, (char*)sA[buf] + base);
      gload_lds16((const char*)B + (size_t)(n0 + row) * 2048 + k0 * 2 + colb, (char*)sB[buf] + base);
    }
  };
  stage(0, 0);
  stage(1, 1);
  for (int kt = 0; kt < 32; ++kt) {
    int cur = kt % 3;
    // own stage(kt) landed (only stage(kt+1)'s 4 loads may remain in flight)
    asm volatile("s_waitcnt vmcnt(4)" ::: "memory");
    __builtin_amdgcn_s_barrier();     // all waves: stage(kt) landed, buf[(kt-1)%3] free
    int kn = (kt + 2 < 32) ? kt + 2 : 31;   // clamp: dup loads into free buffer, harmless
    stage((kt + 2) % 3, kn);
    short8 a[4], b[4];
#pragma unroll
    for (int i = 0; i < 4; ++i) {
      a[i] = *(const short8*)((const char*)sA[cur] + aoff + i * 1024);
      b[i] = *(const short8*)((const char*)sB[cur] + boff + i * 1024);
    }
    __builtin_amdgcn_s_setprio(1);
#pragma unroll
    for (int i = 0; i < 4; ++i)
#pragma unroll
      for (int j = 0; j < 4; ++j)
        acc[i][j] = MFMA16(a[i], b[j], acc[i][j]);
    __builtin_amdgcn_s_setprio(0);
  }
}

// ---------------- QKV projection ----------------
// Writes Q,K as [B*H][S][64] bf16, V transposed as [B*H][64][S] bf16.
__global__ __launch_bounds__(256) void k_qkv_gemm(const u16* __restrict__ xh,
                                                  const u16* __restrict__ wh,
                                                  const float* __restrict__ bqkv,
                                                  u16* __restrict__ Qb, u16* __restrict__ Kb,
                                                  u16* __restrict__ Vt) {
  // XCD swizzle (T1): 768 blocks, 96/XCD -> each XCD owns 4 contiguous m-tiles x all n
  int bid = blockIdx.y * 24 + blockIdx.x;
  int sid = (bid & 7) * 96 + (bid >> 3);
  int m0 = (sid / 24) * 128, n0 = (sid % 24) * 128;
  floatx4 acc[4][4];
  gemm_main(xh, wh, m0, n0, acc);
  const int lane = threadIdx.x & 63, wid = threadIdx.x >> 6;
  const int wr = wid >> 1, wc = wid & 1;
#pragma unroll
  for (int j = 0; j < 4; ++j) {
    int n = n0 + wc * 64 + j * 16 + (lane & 15);
    float bias = bqkv[n];
    int h = n / 192;
    int rr = n - h * 192;
#pragma unroll
    for (int i = 0; i < 4; ++i) {
#pragma unroll
      for (int r = 0; r < 4; ++r) {
        int m = m0 + wr * 64 + i * 16 + (lane >> 4) * 4 + r;
        int b = m >> 11, s = m & 2047;
        float v = acc[i][j][r] + bias;
        u16 bv = f2bf(v);
        int bh = b * 16 + h;
        if (rr < 64)
          Qb[((size_t)bh * 2048 + s) * 64 + rr] = bv;
        else if (rr < 128)
          Kb[((size_t)bh * 2048 + s) * 64 + (rr - 64)] = bv;
        else
          Vt[((size_t)bh * 64 + (rr - 128)) * 2048 + s] = bv;
      }
    }
  }
}

// ---------------- causal flash attention ----------------
// 4 waves x 32 q-rows (two 16-row groups share each K/V fragment read -> LDS reads per
// FLOP halved, 2x MFMA ILP). Swapped QK^T, fixed-max softmax, hoisted swizzle bases.
__global__ __launch_bounds__(256, 2) void k_attn(const u16* __restrict__ Qb,
                                                 const u16* __restrict__ Kb,
                                                 const u16* __restrict__ Vt,
                                                 u16* __restrict__ ao) {
  // balance + L2 remap: bid and bid+256 share bh, qt sums to 15; all blocks of a bh
  // land on XCD bh%8 under round-robin dispatch.
  const int bid = blockIdx.y * 16 + blockIdx.x;
  const int half = bid >> 8, rem = bid & 255;
  const int qtb = rem >> 5, bh = rem & 31;
  const int qt = half ? (15 - qtb) : qtb;
  const int q0 = qt * 128;
  const int tid = threadIdx.x, lane = tid & 63, wid = tid >> 6;   // wid 0..3
  const int cl = lane & 15, hi = lane >> 4;
  const int wq0 = q0 + wid * 32;
  const u16* Qp = Qb + (size_t)bh * (S_LEN * HDIM);
  const u16* Kp = Kb + (size_t)bh * (S_LEN * HDIM);
  const u16* Vp = Vt + (size_t)bh * (HDIM * S_LEN);

  __shared__ __align__(16) u16 Kl[2][64 * 64];
  __shared__ __align__(16) u16 Vl[2][64 * 64];
  __shared__ __align__(16) u16 Pl[4][32 * 72];   // per-wave 32 q-rows x 64 keys, 144B stride

  // hoisted swizzled K/V read bases: b = fc*2048 + cl*128 + kf*64 + hi*16, (b>>7)&7 == cl&7
  const int kvo0 = (cl * 128 + hi * 16) ^ ((cl & 7) << 4);
  const int kvo1 = kvo0 ^ 64;

  short8 qf[2][2];
#pragma unroll
  for (int g = 0; g < 2; ++g)
#pragma unroll
    for (int kf = 0; kf < 2; ++kf)
      qf[g][kf] = *(const short8*)&Qp[(size_t)(wq0 + g * 16 + cl) * 64 + kf * 32 + hi * 8];

  floatx4 o[2][4];
#pragma unroll
  for (int g = 0; g < 2; ++g)
#pragma unroll
    for (int fc = 0; fc < 4; ++fc) o[g][fc] = (floatx4){0.f, 0.f, 0.f, 0.f};
  float lrun[2] = {0.f, 0.f};

  const int NT = 2 * qt + 2;               // block-level tiles (NT >= 2)
  const int NTw = 2 * qt + 1 + (wid >> 1); // this wave's tiles; last one is diagonal
  const float C1 = 0.125f * 1.44269504f;   // scale * log2(e)
  const float C2 = 16.0f * 1.44269504f;    // fixed max * log2(e)

  auto stage = [&](int buf, int kv0) {     // 4 loads/thread (256 threads)
#pragma unroll
    for (int it = 0; it < 2; ++it) {
      int p = (it * 256 + tid) * 16;
      int q = swz(p);
      int row = q >> 7, colb = q & 127;
      int base = (it * 256 + (tid & ~63)) * 16;
      gload_lds16((const char*)Kp + (size_t)(kv0 + row) * 128 + colb, (char*)Kl[buf] + base);
      gload_lds16((const char*)Vp + (size_t)row * 4096 + (size_t)kv0 * 2 + colb, (char*)Vl[buf] + base);
    }
  };
  stage(0, 0);

  for (int t = 0; t < NT; ++t) {
    int cur = t & 1;
    // stage(t) landed (issued one full tile of compute ago -> near-free wait)
    asm volatile("s_waitcnt vmcnt(0)" ::: "memory");
    __builtin_amdgcn_s_barrier();      // all waves: stage(t) landed, buf[t-1] readers done
    if (t + 1 < NT) stage(cur ^ 1, (t + 1) * 64);
    if (t < NTw) {
      int kv0 = t * 64;
      // ---- QK^T (swapped: A=K, B=Q); both q-groups share kfv ----
      floatx4 sc[2][4];
#pragma unroll
      for (int g = 0; g < 2; ++g)
#pragma unroll
        for (int fc = 0; fc < 4; ++fc) sc[g][fc] = (floatx4){0.f, 0.f, 0.f, 0.f};
      __builtin_amdgcn_s_setprio(1);
#pragma unroll
      for (int kf = 0; kf < 2; ++kf) {
        const char* kb = (const char*)Kl[cur] + (kf ? kvo1 : kvo0);
        short8 kfv[4];
#pragma unroll
        for (int fc = 0; fc < 4; ++fc)
          kfv[fc] = *(const short8*)(kb + fc * 2048);
#pragma unroll
        for (int g = 0; g < 2; ++g)
#pragma unroll
          for (int fc = 0; fc < 4; ++fc)
            sc[g][fc] = MFMA16(kfv[fc], qf[g][kf], sc[g][fc]);
      }
      __builtin_amdgcn_s_setprio(0);
      // ---- fixed-max softmax; mask only on the wave's diagonal (last) tile ----
      auto smax = [&](bool masked) {
#pragma unroll
        for (int g = 0; g < 2; ++g) {
          int myq = wq0 + g * 16 + cl;
          float ls = 0.f;
#pragma unroll
          for (int fc = 0; fc < 4; ++fc) {
            float p0 = exp2f(sc[g][fc][0] * C1 - C2);
            float p1 = exp2f(sc[g][fc][1] * C1 - C2);
            float p2 = exp2f(sc[g][fc][2] * C1 - C2);
            float p3 = exp2f(sc[g][fc][3] * C1 - C2);
            if (masked) {
              int key = kv0 + fc * 16 + hi * 4;
              p0 = (key + 0 <= myq) ? p0 : 0.f;
              p1 = (key + 1 <= myq) ? p1 : 0.f;
              p2 = (key + 2 <= myq) ? p2 : 0.f;
              p3 = (key + 3 <= myq) ? p3 : 0.f;
            }
            unsigned r0, r1;
            asm("v_cvt_pk_bf16_f32 %0, %1, %2" : "=v"(r0) : "v"(p0), "v"(p1));
            asm("v_cvt_pk_bf16_f32 %0, %1, %2" : "=v"(r1) : "v"(p2), "v"(p3));
            uint2 rr; rr.x = r0; rr.y = r1;
            *(uint2*)((char*)Pl[wid] + (g * 16 + cl) * 144 + fc * 32 + hi * 8) = rr;
            ls += (p0 + p1) + (p2 + p3);
          }
          lrun[g] += ls;
        }
      };
      if (t == NTw - 1) smax(true); else smax(false);
      // ---- PV: A = P[q][key] (contiguous), B = V^T[d][key]; both groups share vb ----
      __builtin_amdgcn_s_setprio(1);
#pragma unroll
      for (int kf = 0; kf < 2; ++kf) {
        const char* vbp = (const char*)Vl[cur] + (kf ? kvo1 : kvo0);
        short8 pa[2], vb[4];
#pragma unroll
        for (int g = 0; g < 2; ++g)
          pa[g] = *(const short8*)((const char*)Pl[wid] + (g * 16 + cl) * 144 + kf * 64 + hi * 16);
#pragma unroll
        for (int fc = 0; fc < 4; ++fc)
          vb[fc] = *(const short8*)(vbp + fc * 2048);
#pragma unroll
        for (int g = 0; g < 2; ++g)
#pragma unroll
          for (int fc = 0; fc < 4; ++fc)
            o[g][fc] = MFMA16(pa[g], vb[fc], o[g][fc]);
      }
      __builtin_amdgcn_s_setprio(0);
    }
  }
  // ---- epilogue: reduce l across hi-groups, redistribute, normalize, store ----
  const int b = bh >> 4, h = bh & 15;
#pragma unroll
  for (int g = 0; g < 2; ++g) {
    float l = lrun[g];
    l += __shfl_xor(l, 16);
    l += __shfl_xor(l, 32);   // lanes {cl,+16,+32,+48} hold full sum for row g*16+cl
#pragma unroll
    for (int j = 0; j < 4; ++j) {
      float inv = 1.f / __shfl(l, hi * 4 + j);   // full sum for row g*16 + hi*4 + j
      int q = wq0 + g * 16 + hi * 4 + j;
#pragma unroll
      for (int fc = 0; fc < 4; ++fc) {
        size_t idx = ((size_t)b * 2048 + q) * 1024 + h * 64 + fc * 16 + cl;
        ao[idx] = f2bf(o[g][fc][j] * inv);
      }
    }
  }
}

// ---------------- output projection ----------------
__global__ __launch_bounds__(256) void k_out_gemm(const u16* __restrict__ ao,
                                                  const u16* __restrict__ woh,
                                                  const float* __restrict__ bo, float* __restrict__ out) {
  // XCD swizzle (T1): 256 blocks, 32/XCD -> each XCD owns 4 contiguous m-tiles x all n
  int bid = blockIdx.y * 8 + blockIdx.x;
  int sid = (bid & 7) * 32 + (bid >> 3);
  int m0 = (sid >> 3) * 128, n0 = (sid & 7) * 128;
  floatx4 acc[4][4];
  gemm_main(ao, woh, m0, n0, acc);
  const int lane = threadIdx.x & 63, wid = threadIdx.x >> 6;
  const int wr = wid >> 1, wc = wid & 1;
#pragma unroll
  for (int j = 0; j < 4; ++j) {
    int n = n0 + wc * 64 + j * 16 + (lane & 15);
    float bias = bo[n];
#pragma unroll
    for (int i = 0; i < 4; ++i) {
#pragma unroll
      for (int r = 0; r < 4; ++r) {
        int m = m0 + wr * 64 + i * 16 + (lane >> 4) * 4 + r;
        out[(size_t)m * 1024 + n] = acc[i][j][r] + bias;
      }
    }
  }
}

// ---------------- launch ----------------
extern "C" void kernel_launch(void* const* d_in, const int* in_sizes, int n_in,
                              void* d_out, int out_size, void* d_ws, size_t ws_size,
                              hipStream_t stream) {
  (void)in_sizes; (void)n_in; (void)out_size; (void)ws_size;
  const float* x    = (const float*)d_in[0];
  // d_in[1] = causal mask (tril) — implied by kernel structure, not read
  const float* Wqkv = (const float*)d_in[2];
  const float* bqkv = (const float*)d_in[3];
  const float* Wo   = (const float*)d_in[4];
  const float* bo   = (const float*)d_in[5];
  float* out = (float*)d_out;

  u16* p = (u16*)d_ws;
  u16* xh  = p; p += 4194304;   // [4096][1024] — reused as ao after QKV GEMM
  u16* wh  = p; p += 3145728;   // WqkvT [3072][1024] bf16
  u16* woh = p; p += 1048576;   // WoT   [1024][1024] bf16
  u16* Qb  = p; p += 4194304;   // [B*H][S][64]
  u16* Kb  = p; p += 4194304;
  u16* Vt  = p; p += 4194304;   // [B*H][64][S]
  u16* ao  = xh;                // alias: x dead after QKV GEMM

  k_cast<<<4096, 256, 0, stream>>>(x, xh, 4194304);
  k_transpose<<<dim3(96, 32), dim3(32, 8), 0, stream>>>(Wqkv, wh, 1024, 3072);
  k_transpose<<<dim3(32, 32), dim3(32, 8), 0, stream>>>(Wo, woh, 1024, 1024);
  k_qkv_gemm<<<dim3(24, 32), 256, 0, stream>>>(xh, wh, bqkv, Qb, Kb, Vt);
  k_attn<<<dim3(16, 32), 256, 0, stream>>>(Qb, Kb, Vt, ao);
  k_out_gemm<<<dim3(8, 32), 256, 0, stream>>>(ao, woh, bo, out);
}